// Round 6
// baseline (424.942 us; speedup 1.0000x reference)
//
#include <hip/hip_runtime.h>
#include <hip/hip_bf16.h>

// Problem constants
#define NN 240        // rows (tokens)
#define CC 6144       // channels
#define DD 3072       // head dim
#define C3 18432      // 3*C
#define HH 2          // heads

typedef __attribute__((ext_vector_type(8))) short bf16x8;
typedef __attribute__((ext_vector_type(4))) float f32x4;
typedef unsigned short ushort_t;

static __device__ __forceinline__ unsigned short f2bf(float f) {
    __hip_bfloat16 h = __float2bfloat16(f);
    return __builtin_bit_cast(unsigned short, h);
}

// global -> LDS direct DMA, 16 B per lane, LDS dest wave-uniform base.
#define GLDS16(g, l) __builtin_amdgcn_global_load_lds( \
    (const __attribute__((address_space(1))) void*)(g), \
    (__attribute__((address_space(3))) void*)(l), 16, 0, 0)

// C[240 x N] = A_bf16[256 x K] * B_fp32[N x K]^T (+bias on kc==0), split-K.
// BM=256 (all rows), BN=32, BK=64. 8 waves (4M x 2N), per-wave 64x16.
// LDS 72 KB -> 2 blocks/CU (TLP covers barrier parks). Uniform-issue pipeline:
// every step issues exactly 4 A-DMA + 1 B-load (tail steps issue clamped
// dummies so vmcnt counts stay uniform). Waits:
//   top-of-step  vmcnt(6): A(t) complete (issued 1 full step earlier)
//   pre-B-write  vmcnt(5): B(t+1) regs complete (issued 2 steps earlier)
// Never drains to 0 in the main loop.
__global__ __launch_bounds__(512, 4)
void gemm_v6(const ushort_t* __restrict__ Ab, int lda, long long sAz,
             const float* __restrict__ B, int ldb, long long sBz,
             const float* __restrict__ bias,
             float* __restrict__ C0, long long sC0z,
             float* __restrict__ CP, long long sCPz,
             int ldc, int N, int Kc, int KS,
             ushort_t* __restrict__ Qb) {
    __shared__ ushort_t sA[2][256 * 64];   // 2 x 32 KB
    __shared__ ushort_t sB[2][32 * 64];    // 2 x 4 KB   (72 KB total)

    const int zc = blockIdx.z;
    const int z = zc / KS, kc = zc % KS;
    const ushort_t* Abase = Ab + (size_t)z * sAz + (size_t)kc * Kc;
    const float*    Bbase = B  + (size_t)z * sBz + (size_t)kc * Kc;
    float* Cw = (kc == 0) ? (C0 + (size_t)z * sC0z)
                          : (CP + (size_t)(z * (KS - 1) + kc - 1) * sCPz);

    const int n0 = blockIdx.x * 32;
    const int tid = threadIdx.x, lane = tid & 63, wid = tid >> 6;
    const int wm = wid >> 1, wn = wid & 1;
    const int l16 = lane & 15, lk = lane >> 4;

    // A DMA source: chunk c=wid*4+i covers LDS rows c*8..c*8+7 (128 B/row).
    // Lane l -> row c*8+(l>>3); slot l&7 holds source octet (l&7)^(row&7)
    // so the XOR'd ds_read recovers linear k. (Proven zero-conflict.)
    const int arow = wid * 32 + (lane >> 3);
    const ushort_t* ap = Abase + (size_t)arow * lda
                         + ((lane & 7) ^ ((lane >> 3) & 7)) * 8;

    // B: thread t -> row t>>4 (0..31, clamped to N-1), k-quad q=t&15.
    const int brow = tid >> 4, bq = tid & 15;
    int brow_c = n0 + brow; if (brow_c > N - 1) brow_c = N - 1;
    const float* bp = Bbase + (size_t)brow_c * ldb + bq * 4;
    // LDS write: 16B slot (bq>>1) XOR row&7, half-slot bq&1 (8 B write).
    const int bws = brow * 128 + ((((bq >> 1) ^ (brow & 7)) << 4) + (bq & 1) * 8);

    const int nt = Kc / 64;                 // 96 / 32 / 2 — always even
    f32x4 acc[4] = {};                      // 4 mt x 1 nf

    auto ISSUE_A = [&](int t, int par) {
        const ushort_t* a = ap + (size_t)t * 64;
#pragma unroll
        for (int i = 0; i < 4; ++i)
            GLDS16(a + (size_t)i * 8 * lda, &sA[par][(wid * 4 + i) * 512]);
    };
    auto LOAD_B = [&](int t) {
        return *(const float4*)(bp + (size_t)t * 64);
    };
    auto WRITE_B = [&](int par, float4 g) {
        ushort4 u;
        u.x = f2bf(g.x); u.y = f2bf(g.y); u.z = f2bf(g.z); u.w = f2bf(g.w);
        *(ushort4*)(reinterpret_cast<char*>(&sB[par][0]) + bws) = u;
    };
    auto MFMA_PH = [&](int cur) {
        const char* As = (const char*)sA[cur];
        const char* Bs = (const char*)sB[cur];
#pragma unroll
        for (int ks = 0; ks < 2; ++ks) {
            bf16x8 af[4], bf1;
#pragma unroll
            for (int mt = 0; mt < 4; ++mt) {
                int row = wm * 64 + mt * 16 + l16;
                int boff = row * 128 + (((ks * 4 + lk) * 16) ^ ((row & 7) << 4));
                af[mt] = *(const bf16x8*)(As + boff);
            }
            {
                int row = wn * 16 + l16;
                int boff = row * 128 + (((ks * 4 + lk) * 16) ^ ((row & 7) << 4));
                bf1 = *(const bf16x8*)(Bs + boff);
            }
            __builtin_amdgcn_s_setprio(1);
#pragma unroll
            for (int mt = 0; mt < 4; ++mt)
                acc[mt] = __builtin_amdgcn_mfma_f32_16x16x32_bf16(
                    af[mt], bf1, acc[mt], 0, 0, 0);
            __builtin_amdgcn_s_setprio(0);
        }
    };

    float4 e, o;    // static even/odd B register sets (rule #20)

    // Prologue: A(0) DMA; B(0)->e, B(1)->o; drain A(0),B(0); write B(0).
    ISSUE_A(0, 0);
    e = LOAD_B(0);
    o = (nt > 1) ? LOAD_B(1) : e;
    asm volatile("s_waitcnt vmcnt(1)" ::: "memory");   // allow B(1) in flight
    __builtin_amdgcn_sched_barrier(0);
    WRITE_B(0, e);
    asm volatile("s_waitcnt lgkmcnt(0)" ::: "memory");
    __builtin_amdgcn_s_barrier();

    // STEP(t): w <- B(min(t+2,nt-1)); write r = B(t+1) to LDS at step end.
    auto STEP = [&](int t, float4& w, float4& r) {
        int ta = t + 1 < nt ? t + 1 : nt - 1;
        int tb = t + 2 < nt ? t + 2 : nt - 1;
        ISSUE_A(ta, (t + 1) & 1);          // 4 ops (dummy at tail, same count)
        w = LOAD_B(tb);                    // 1 op
        __builtin_amdgcn_sched_barrier(0);
        asm volatile("s_waitcnt vmcnt(6)" ::: "memory");  // A(t) + older done
        __builtin_amdgcn_sched_barrier(0);
        MFMA_PH(t & 1);
        __builtin_amdgcn_sched_barrier(0);
        asm volatile("s_waitcnt vmcnt(5)" ::: "memory");  // B(t+1) regs done
        __builtin_amdgcn_sched_barrier(0);
        WRITE_B((t + 1) & 1, r);
        asm volatile("s_waitcnt lgkmcnt(0)" ::: "memory");
        __builtin_amdgcn_s_barrier();
    };

    for (int t = 0; t < nt; t += 2) {
        STEP(t,     e, o);
        STEP(t + 1, o, e);
    }

    // Epilogue: fragment row = lk*4+j, col = l16
#pragma unroll
    for (int mt = 0; mt < 4; ++mt) {
#pragma unroll
        for (int j = 0; j < 4; ++j) {
            int grow = wm * 64 + mt * 16 + lk * 4 + j;
            if (grow < NN) {
                int gcol = n0 + wn * 16 + l16;
                if (gcol < N) {
                    float v = acc[mt][j];
                    if (kc == 0 && bias) v += bias[gcol];
                    Cw[(size_t)grow * ldc + gcol] = v;
                    if (Qb && gcol < CC)
                        Qb[(size_t)grow * CC + gcol] = f2bf(v);
                }
            }
        }
    }
}

// xb = bf16(x), rows 240..255 zeroed.
__global__ __launch_bounds__(256)
void convert_kernel(const float* __restrict__ x, ushort_t* __restrict__ xb) {
    int id = blockIdx.x * 256 + threadIdx.x;      // 196608 = 256*6144/8
    int row = id / 768, c8 = id % 768;
    bf16x8 o = {};
    if (row < NN) {
        const float* p = x + (size_t)row * CC + c8 * 8;
        float4 a = *(const float4*)p, b = *(const float4*)(p + 4);
        o[0] = (short)f2bf(a.x); o[1] = (short)f2bf(a.y);
        o[2] = (short)f2bf(a.z); o[3] = (short)f2bf(a.w);
        o[4] = (short)f2bf(b.x); o[5] = (short)f2bf(b.y);
        o[6] = (short)f2bf(b.z); o[7] = (short)f2bf(b.w);
    }
    *(bf16x8*)(xb + (size_t)row * CC + c8 * 8) = o;
}

// out += 2 partials (proj split-K reduce; bias added by kc==0 path)
__global__ __launch_bounds__(256)
void reduce_proj(float4* __restrict__ o4, const float4* __restrict__ p4,
                 long long s4) {
    int i = blockIdx.x * 256 + threadIdx.x;    // 368,640 float4s
    float4 a = o4[i];
#pragma unroll
    for (int k = 0; k < 2; ++k) {
        float4 b = p4[(size_t)k * s4 + i];
        a.x += b.x; a.y += b.y; a.z += b.z; a.w += b.w;
    }
    o4[i] = a;
}

// qmax[(h*240+n)*12 + c] = max over q[h][n][c*256 .. c*256+255]
__global__ __launch_bounds__(256)
void qmax_kernel(const float* __restrict__ qkv, float* __restrict__ qmax) {
    int idx = blockIdx.x * 4 + (threadIdx.x >> 6);   // 0..5759
    int lane = threadIdx.x & 63;
    int c = idx % 12;
    int r = idx / 12;            // h*240 + n
    int n = r % NN, h = r / NN;
    const float* p = qkv + (size_t)n * C3 + h * DD + c * 256 + lane * 4;
    float4 f = *(const float4*)p;
    float m = fmaxf(fmaxf(f.x, f.y), fmaxf(f.z, f.w));
#pragma unroll
    for (int off = 32; off >= 1; off >>= 1)
        m = fmaxf(m, __shfl_xor(m, off));
    if (lane == 0) qmax[idx] = m;
}

// Softmax rows of (scale * (attn + sum partials) + 0.1*Pq), in place.
__global__ __launch_bounds__(256)
void softmax_kernel(float* __restrict__ attn, const float* __restrict__ gpart,
                    int ksm1, const float* __restrict__ qmax) {
    int r = blockIdx.x * 4 + (threadIdx.x >> 6);   // 0..479 = z*240+n
    int lane = threadIdx.x & 63;
    int z = r / NN, n = r % NN;
    float* row = attn + (size_t)r * NN;
    const float* qm = qmax + r * 12;
    const float scale = 0.0180421959f;             // 3072^-0.5
    float v[4];
    float mx = -1e30f;
#pragma unroll
    for (int i = 0; i < 4; ++i) {
        int m = lane + 64 * i;
        v[i] = -1e30f;
        if (m < NN) {
            float s = row[m];
            for (int kc = 0; kc < ksm1; ++kc)
                s += gpart[(size_t)(z * ksm1 + kc) * (NN * NN)
                           + (size_t)n * NN + m];
            v[i] = s * scale + 0.1f * qm[m % 12];
        }
        mx = fmaxf(mx, v[i]);
    }
#pragma unroll
    for (int off = 32; off >= 1; off >>= 1)
        mx = fmaxf(mx, __shfl_xor(mx, off));
    float s = 0.f;
#pragma unroll
    for (int i = 0; i < 4; ++i) {
        v[i] = __expf(v[i] - mx);
        s += v[i];
    }
#pragma unroll
    for (int off = 32; off >= 1; off >>= 1)
        s += __shfl_xor(s, off);
    float inv = 1.0f / s;
#pragma unroll
    for (int i = 0; i < 4; ++i) {
        int m = lane + 64 * i;
        if (m < NN) row[m] = v[i] * inv;
    }
}

// preb[n][h*3072+dd] = bf16( sum_m attn[h][n][m] * v[h][m][dd] )
__global__ __launch_bounds__(256)
void pv_kernel(const float* __restrict__ attn, const float* __restrict__ qkv,
               ushort_t* __restrict__ preb) {
    const int h = blockIdx.z;
    const int n0 = blockIdx.y * 16;
    const int dd0 = blockIdx.x * 256;
    __shared__ float s_attn[16 * NN];
    for (int i = threadIdx.x; i < 16 * NN; i += 256)
        s_attn[i] = attn[(size_t)h * NN * NN + (n0 + i / NN) * NN + (i % NN)];
    __syncthreads();

    const float* vp = qkv + 2 * CC + h * DD + dd0 + threadIdx.x;
    float acc[16] = {};
    for (int m = 0; m < NN; m += 4) {
        float v0 = vp[(size_t)(m + 0) * C3];
        float v1 = vp[(size_t)(m + 1) * C3];
        float v2 = vp[(size_t)(m + 2) * C3];
        float v3 = vp[(size_t)(m + 3) * C3];
#pragma unroll
        for (int i = 0; i < 16; ++i) {
            float4 a = *(const float4*)&s_attn[i * NN + m];
            acc[i] += a.x * v0 + a.y * v1 + a.z * v2 + a.w * v3;
        }
    }
#pragma unroll
    for (int i = 0; i < 16; ++i)
        preb[(size_t)(n0 + i) * CC + h * DD + dd0 + threadIdx.x] =
            f2bf(acc[i]);
}

extern "C" void kernel_launch(void* const* d_in, const int* in_sizes, int n_in,
                              void* d_out, int out_size, void* d_ws, size_t ws_size,
                              hipStream_t stream) {
    const float* x      = (const float*)d_in[0];
    const float* w_qkv  = (const float*)d_in[1];
    const float* w_proj = (const float*)d_in[2];
    const float* b_proj = (const float*)d_in[3];
    float* out = (float*)d_out;

    // ws layout (floats): qkv 4.42M | attn 115K | qmax 5.8K |
    // xb,qb,preb (bf16 256x6144 each) | gpart 2x4.42M   => ~45.3 MB
    const size_t f_qkv  = (size_t)NN * C3;
    const size_t f_attn = (size_t)HH * NN * NN;
    const size_t f_qmax = (size_t)HH * NN * 12;
    float* qkv   = (float*)d_ws;
    float* attn  = qkv + f_qkv;
    float* qmaxb = attn + f_attn;
    ushort_t* xb   = (ushort_t*)(qmaxb + f_qmax);
    ushort_t* qb   = xb + (size_t)256 * CC;
    ushort_t* preb = qb + (size_t)256 * CC;
    float* gpart = (float*)(preb + (size_t)256 * CC);

    // 0. bf16 conversion of x (zero-padded to 256 rows)
    convert_kernel<<<768, 256, 0, stream>>>(x, xb);

    // 1. qkv = x @ w_qkv^T  (576 blocks, nt=96; epilogue emits bf16 Q)
    gemm_v6<<<dim3(C3 / 32, 1, 1), 512, 0, stream>>>(
        xb, CC, 0LL, w_qkv, CC, 0LL, nullptr,
        qkv, 0LL, gpart, 0LL,
        C3, C3, CC, 1, qb);

    // 2. Pq maxpool over q
    qmax_kernel<<<1440, 256, 0, stream>>>(qkv, qmaxb);

    // 3. attn_raw = Q @ K^T per head (KS=24, nt=2: kc0 -> attn, rest -> gpart)
    gemm_v6<<<dim3(8, 1, HH * 24), 512, 0, stream>>>(
        qb, CC, (long long)DD,
        qkv + CC, C3, (long long)DD, nullptr,
        attn, (long long)(NN * NN), gpart, (long long)(NN * NN),
        NN, NN, DD / 24, 24, nullptr);

    // 4. softmax (fuses split-K reduce, scale, +0.1*Pq)
    softmax_kernel<<<120, 256, 0, stream>>>(attn, gpart, 23, qmaxb);

    // 5. preb = bf16(attn @ V)
    pv_kernel<<<dim3(12, 15, HH), 256, 0, stream>>>(attn, qkv, preb);

    // 6. out = pre @ w_proj^T + b_proj (KS=3, nt=32: kc0 -> out+bias)
    gemm_v6<<<dim3(CC / 32, 1, 3), 512, 0, stream>>>(
        preb, CC, 0LL, w_proj, CC, 0LL, b_proj,
        out, 0LL, gpart, (long long)((size_t)NN * CC),
        CC, CC, CC / 3, 3, nullptr);
    reduce_proj<<<1440, 256, 0, stream>>>((float4*)out, (const float4*)gpart,
        (long long)((size_t)NN * CC / 4));
}

// Round 7
// 404.660 us; speedup vs baseline: 1.0501x; 1.0501x over previous
//
#include <hip/hip_runtime.h>
#include <hip/hip_bf16.h>

// Problem constants
#define NN 240        // rows (tokens)
#define CC 6144       // channels
#define DD 3072       // head dim
#define C3 18432      // 3*C
#define HH 2          // heads

typedef __attribute__((ext_vector_type(8))) short bf16x8;
typedef __attribute__((ext_vector_type(4))) float f32x4;
typedef unsigned short ushort_t;

static __device__ __forceinline__ unsigned short f2bf(float f) {
    __hip_bfloat16 h = __float2bfloat16(f);
    return __builtin_bit_cast(unsigned short, h);
}

// global -> LDS direct DMA, 16 B per lane, LDS dest wave-uniform base.
#define GLDS16(g, l) __builtin_amdgcn_global_load_lds( \
    (const __attribute__((address_space(1))) void*)(g), \
    (__attribute__((address_space(3))) void*)(l), 16, 0, 0)

// C[240 x N] = A_bf16[256 x K] * B_fp32[N x K]^T (+bias on kc==0), split-K.
// BM=256 (all rows), BN=64, BK=64. 256 threads = 4 waves, layout 1M x 4N:
// each wave owns 16 output cols x all 256 rows (acc = 16 f32x4).
// B NEVER touches LDS: per-wave global->VGPR loads in exact MFMA B-fragment
// layout (lane=col l16, lk=k-octet), fp32->bf16 cvt in regs, depth-2
// register pipeline (static even/odd sets). Each weight element is loaded
// exactly once per block (wave covers all M) -> no duplicate cvt.
// A (L2-resident) keeps the LDS dbuf via global_load_lds with the proven
// XOR-swizzled-source layout. One vmcnt(4) + one s_barrier per k64 step;
// B loads stay in flight across the barrier (never drained to 0).
__global__ __launch_bounds__(256, 2)
void gemm_rs(const ushort_t* __restrict__ Ab, int lda, long long sAz,
             const float* __restrict__ B, int ldb, long long sBz,
             const float* __restrict__ bias,
             float* __restrict__ C0, long long sC0z,
             float* __restrict__ CP, long long sCPz,
             int ldc, int N, int Kc, int KS,
             ushort_t* __restrict__ Qb) {
    __shared__ ushort_t sA[2][256 * 64];   // 2 x 32 KB -> 2 blocks/CU

    const int zc = blockIdx.z;
    const int z = zc / KS, kc = zc % KS;
    const ushort_t* Abase = Ab + (size_t)z * sAz + (size_t)kc * Kc;
    const float*    Bbase = B  + (size_t)z * sBz + (size_t)kc * Kc;
    float* Cw = (kc == 0) ? (C0 + (size_t)z * sC0z)
                          : (CP + (size_t)(z * (KS - 1) + kc - 1) * sCPz);

    const int n0 = blockIdx.x * 64;
    const int tid = threadIdx.x, lane = tid & 63, wid = tid >> 6;  // 4 waves
    const int l16 = lane & 15, lk = lane >> 4;

    // A DMA source: wave w covers rows w*64..w*64+63 (8 chunks of 8 rows).
    // Lane l -> row chunk*8+(l>>3); slot l&7 holds source octet (l&7)^(row&7)
    // so the XOR'd ds_read recovers linear k. (Proven zero-conflict.)
    const ushort_t* ap = Abase + (size_t)(wid * 64 + (lane >> 3)) * lda
                         + ((lane & 7) ^ ((lane >> 3) & 7)) * 8;

    // B: lane reads its own MFMA fragment: col = n0 + wid*16 + l16 (clamped),
    // k-octet lk*8. Two float4 per k32 phase.
    int colc = n0 + wid * 16 + l16; if (colc > N - 1) colc = N - 1;
    const float* bp = Bbase + (size_t)colc * ldb + lk * 8;

    const int nt = Kc / 64;                 // 96 / 32 / 2 — always even
    f32x4 acc[16] = {};

    auto ISSUE_A = [&](int u, int par) {    // 8 GLDS into sA[par]
        const ushort_t* a = ap + (size_t)u * 64;
        ushort_t* d = &sA[par][wid * 8 * 512];
#pragma unroll
        for (int i = 0; i < 8; ++i)
            GLDS16(a + (size_t)i * 8 * lda, d + i * 512);
    };
    auto LOAD_B4 = [&](int u, float4& b0, float4& b1, float4& b2, float4& b3) {
        const float* p = bp + (size_t)u * 64;
        b0 = *(const float4*)p;            // phase0: k = u*64 + lk*8 .. +4
        b1 = *(const float4*)(p + 4);      // phase0: +4 .. +8
        b2 = *(const float4*)(p + 32);     // phase1
        b3 = *(const float4*)(p + 36);
    };
    auto PHASE = [&](int buf, int ph, float4 g0, float4 g1) {
        bf16x8 bfr;
        bfr[0] = (short)f2bf(g0.x); bfr[1] = (short)f2bf(g0.y);
        bfr[2] = (short)f2bf(g0.z); bfr[3] = (short)f2bf(g0.w);
        bfr[4] = (short)f2bf(g1.x); bfr[5] = (short)f2bf(g1.y);
        bfr[6] = (short)f2bf(g1.z); bfr[7] = (short)f2bf(g1.w);
        const char* As = (const char*)sA[buf];
        __builtin_amdgcn_s_setprio(1);
#pragma unroll
        for (int mt = 0; mt < 16; ++mt) {
            int row = mt * 16 + l16;
            int boff = row * 128 + (((ph * 4 + lk) * 16) ^ ((row & 7) << 4));
            bf16x8 af = *(const bf16x8*)(As + boff);
            acc[mt] = __builtin_amdgcn_mfma_f32_16x16x32_bf16(
                af, bfr, acc[mt], 0, 0, 0);
        }
        __builtin_amdgcn_s_setprio(0);
    };

    float4 e0, e1, e2, e3, o0, o1, o2, o3;   // static even/odd B sets

    // Prologue: A(0) -> buf0; B(0) -> even set; B(1) -> odd set.
    ISSUE_A(0, 0);
    LOAD_B4(0, e0, e1, e2, e3);
    LOAD_B4(nt > 1 ? 1 : 0, o0, o1, o2, o3);
    __builtin_amdgcn_sched_barrier(0);

    // STEP(t): wait A(t) (vmcnt(4): only B(t+1)x4 newer) -> barrier ->
    // issue A(t+1) (post-barrier: all waves done reading sA[(t+1)&1]) ->
    // 2 MFMA phases from regs r* -> issue B(t+2) into the just-freed set w*.
    auto STEP = [&](int t,
                    float4& r0, float4& r1, float4& r2, float4& r3,
                    float4& w0, float4& w1, float4& w2, float4& w3) {
        asm volatile("s_waitcnt vmcnt(4)" ::: "memory");
        __builtin_amdgcn_s_barrier();
        __builtin_amdgcn_sched_barrier(0);
        int ua = t + 1 < nt ? t + 1 : nt - 1;    // tail: dummy into other buf
        ISSUE_A(ua, (t + 1) & 1);
        __builtin_amdgcn_sched_barrier(0);
        PHASE(t & 1, 0, r0, r1);
        PHASE(t & 1, 1, r2, r3);
        __builtin_amdgcn_sched_barrier(0);
        int ub = t + 2 < nt ? t + 2 : nt - 1;    // tail: dummy regs
        LOAD_B4(ub, w0, w1, w2, w3);
        __builtin_amdgcn_sched_barrier(0);
    };

    for (int t = 0; t < nt; t += 2) {
        STEP(t,     e0, e1, e2, e3, e0, e1, e2, e3);
        STEP(t + 1, o0, o1, o2, o3, o0, o1, o2, o3);
    }

    // Epilogue: acc[mt] -> rows mt*16 + lk*4 + j, col n0 + wid*16 + l16
#pragma unroll
    for (int mt = 0; mt < 16; ++mt) {
#pragma unroll
        for (int j = 0; j < 4; ++j) {
            int grow = mt * 16 + lk * 4 + j;
            if (grow < NN) {
                int gcol = n0 + wid * 16 + l16;
                if (gcol < N) {
                    float v = acc[mt][j];
                    if (kc == 0 && bias) v += bias[gcol];
                    Cw[(size_t)grow * ldc + gcol] = v;
                    if (Qb && gcol < CC)
                        Qb[(size_t)grow * CC + gcol] = f2bf(v);
                }
            }
        }
    }
}

// xb = bf16(x), rows 240..255 zeroed.
__global__ __launch_bounds__(256)
void convert_kernel(const float* __restrict__ x, ushort_t* __restrict__ xb) {
    int id = blockIdx.x * 256 + threadIdx.x;      // 196608 = 256*6144/8
    int row = id / 768, c8 = id % 768;
    bf16x8 o = {};
    if (row < NN) {
        const float* p = x + (size_t)row * CC + c8 * 8;
        float4 a = *(const float4*)p, b = *(const float4*)(p + 4);
        o[0] = (short)f2bf(a.x); o[1] = (short)f2bf(a.y);
        o[2] = (short)f2bf(a.z); o[3] = (short)f2bf(a.w);
        o[4] = (short)f2bf(b.x); o[5] = (short)f2bf(b.y);
        o[6] = (short)f2bf(b.z); o[7] = (short)f2bf(b.w);
    }
    *(bf16x8*)(xb + (size_t)row * CC + c8 * 8) = o;
}

// out += 2 partials (proj split-K reduce; bias added by kc==0 path)
__global__ __launch_bounds__(256)
void reduce_proj(float4* __restrict__ o4, const float4* __restrict__ p4,
                 long long s4) {
    int i = blockIdx.x * 256 + threadIdx.x;    // 368,640 float4s
    float4 a = o4[i];
#pragma unroll
    for (int k = 0; k < 2; ++k) {
        float4 b = p4[(size_t)k * s4 + i];
        a.x += b.x; a.y += b.y; a.z += b.z; a.w += b.w;
    }
    o4[i] = a;
}

// qmax[(h*240+n)*12 + c] = max over q[h][n][c*256 .. c*256+255]
__global__ __launch_bounds__(256)
void qmax_kernel(const float* __restrict__ qkv, float* __restrict__ qmax) {
    int idx = blockIdx.x * 4 + (threadIdx.x >> 6);   // 0..5759
    int lane = threadIdx.x & 63;
    int c = idx % 12;
    int r = idx / 12;            // h*240 + n
    int n = r % NN, h = r / NN;
    const float* p = qkv + (size_t)n * C3 + h * DD + c * 256 + lane * 4;
    float4 f = *(const float4*)p;
    float m = fmaxf(fmaxf(f.x, f.y), fmaxf(f.z, f.w));
#pragma unroll
    for (int off = 32; off >= 1; off >>= 1)
        m = fmaxf(m, __shfl_xor(m, off));
    if (lane == 0) qmax[idx] = m;
}

// Softmax rows of (scale * (attn + sum partials) + 0.1*Pq), in place.
__global__ __launch_bounds__(256)
void softmax_kernel(float* __restrict__ attn, const float* __restrict__ gpart,
                    int ksm1, const float* __restrict__ qmax) {
    int r = blockIdx.x * 4 + (threadIdx.x >> 6);   // 0..479 = z*240+n
    int lane = threadIdx.x & 63;
    int z = r / NN, n = r % NN;
    float* row = attn + (size_t)r * NN;
    const float* qm = qmax + r * 12;
    const float scale = 0.0180421959f;             // 3072^-0.5
    float v[4];
    float mx = -1e30f;
#pragma unroll
    for (int i = 0; i < 4; ++i) {
        int m = lane + 64 * i;
        v[i] = -1e30f;
        if (m < NN) {
            float s = row[m];
            for (int kc = 0; kc < ksm1; ++kc)
                s += gpart[(size_t)(z * ksm1 + kc) * (NN * NN)
                           + (size_t)n * NN + m];
            v[i] = s * scale + 0.1f * qm[m % 12];
        }
        mx = fmaxf(mx, v[i]);
    }
#pragma unroll
    for (int off = 32; off >= 1; off >>= 1)
        mx = fmaxf(mx, __shfl_xor(mx, off));
    float s = 0.f;
#pragma unroll
    for (int i = 0; i < 4; ++i) {
        v[i] = __expf(v[i] - mx);
        s += v[i];
    }
#pragma unroll
    for (int off = 32; off >= 1; off >>= 1)
        s += __shfl_xor(s, off);
    float inv = 1.0f / s;
#pragma unroll
    for (int i = 0; i < 4; ++i) {
        int m = lane + 64 * i;
        if (m < NN) row[m] = v[i] * inv;
    }
}

// preb[n][h*3072+dd] = bf16( sum_m attn[h][n][m] * v[h][m][dd] )
__global__ __launch_bounds__(256)
void pv_kernel(const float* __restrict__ attn, const float* __restrict__ qkv,
               ushort_t* __restrict__ preb) {
    const int h = blockIdx.z;
    const int n0 = blockIdx.y * 16;
    const int dd0 = blockIdx.x * 256;
    __shared__ float s_attn[16 * NN];
    for (int i = threadIdx.x; i < 16 * NN; i += 256)
        s_attn[i] = attn[(size_t)h * NN * NN + (n0 + i / NN) * NN + (i % NN)];
    __syncthreads();

    const float* vp = qkv + 2 * CC + h * DD + dd0 + threadIdx.x;
    float acc[16] = {};
    for (int m = 0; m < NN; m += 4) {
        float v0 = vp[(size_t)(m + 0) * C3];
        float v1 = vp[(size_t)(m + 1) * C3];
        float v2 = vp[(size_t)(m + 2) * C3];
        float v3 = vp[(size_t)(m + 3) * C3];
#pragma unroll
        for (int i = 0; i < 16; ++i) {
            float4 a = *(const float4*)&s_attn[i * NN + m];
            acc[i] += a.x * v0 + a.y * v1 + a.z * v2 + a.w * v3;
        }
    }
#pragma unroll
    for (int i = 0; i < 16; ++i)
        preb[(size_t)(n0 + i) * CC + h * DD + dd0 + threadIdx.x] =
            f2bf(acc[i]);
}

extern "C" void kernel_launch(void* const* d_in, const int* in_sizes, int n_in,
                              void* d_out, int out_size, void* d_ws, size_t ws_size,
                              hipStream_t stream) {
    const float* x      = (const float*)d_in[0];
    const float* w_qkv  = (const float*)d_in[1];
    const float* w_proj = (const float*)d_in[2];
    const float* b_proj = (const float*)d_in[3];
    float* out = (float*)d_out;

    // ws layout (floats): qkv 4.42M | attn 115K | qmax 5.8K |
    // xb,qb,preb (bf16 256x6144 each) | gpart 4.42M   => ~45.3 MB
    const size_t f_qkv  = (size_t)NN * C3;
    const size_t f_attn = (size_t)HH * NN * NN;
    const size_t f_qmax = (size_t)HH * NN * 12;
    float* qkv   = (float*)d_ws;
    float* attn  = qkv + f_qkv;
    float* qmaxb = attn + f_attn;
    ushort_t* xb   = (ushort_t*)(qmaxb + f_qmax);
    ushort_t* qb   = xb + (size_t)256 * CC;
    ushort_t* preb = qb + (size_t)256 * CC;
    float* gpart = (float*)(preb + (size_t)256 * CC);

    // 0. bf16 conversion of x (zero-padded to 256 rows)
    convert_kernel<<<768, 256, 0, stream>>>(x, xb);

    // 1. qkv = x @ w_qkv^T  (288 blocks, nt=96; epilogue emits bf16 Q)
    gemm_rs<<<dim3(C3 / 64, 1, 1), 256, 0, stream>>>(
        xb, CC, 0LL, w_qkv, CC, 0LL, nullptr,
        qkv, 0LL, gpart, 0LL,
        C3, C3, CC, 1, qb);

    // 2. Pq maxpool over q
    qmax_kernel<<<1440, 256, 0, stream>>>(qkv, qmaxb);

    // 3. attn_raw = Q @ K^T per head (KS=24, nt=2: kc0 -> attn, rest -> gpart)
    gemm_rs<<<dim3(4, 1, HH * 24), 256, 0, stream>>>(
        qb, CC, (long long)DD,
        qkv + CC, C3, (long long)DD, nullptr,
        attn, (long long)(NN * NN), gpart, (long long)(NN * NN),
        NN, NN, DD / 24, 24, nullptr);

    // 4. softmax (fuses split-K reduce, scale, +0.1*Pq)
    softmax_kernel<<<120, 256, 0, stream>>>(attn, gpart, 23, qmaxb);

    // 5. preb = bf16(attn @ V)
    pv_kernel<<<dim3(12, 15, HH), 256, 0, stream>>>(attn, qkv, preb);

    // 6. out = pre @ w_proj^T + b_proj (KS=3, nt=32: kc0 -> out+bias)
    gemm_rs<<<dim3(CC / 64, 1, 3), 256, 0, stream>>>(
        preb, CC, 0LL, w_proj, CC, 0LL, b_proj,
        out, 0LL, gpart, (long long)((size_t)NN * CC),
        CC, CC, CC / 3, 3, nullptr);
    reduce_proj<<<1440, 256, 0, stream>>>((float4*)out, (const float4*)gpart,
        (long long)((size_t)NN * CC / 4));
}